// Round 1
// baseline (963.485 us; speedup 1.0000x reference)
//
#include <hip/hip_runtime.h>
#include <math.h>
#include <float.h>

// Problem constants (match reference)
#define B_ 2048
#define D_ 512
#define T_ 16
#define H_ 1024
#define K_ 50
#define M_ 16
#define NSWEEP 8   // one-sided Jacobi sweeps; tune down later with measured margin

__device__ __forceinline__ float bsum64(float v) {
  #pragma unroll
  for (int o = 1; o < 64; o <<= 1) v += __shfl_xor(v, o);
  return v;
}

// act[b,h] = (1 - tanh^2(z)) * W2[h],  z = concat(x,t)[b,:] @ W1[:,h] + b1[h]
// M=2048, N=1024, K=528.  NN GEMM, 64x64x16 tiles, 4x4 microtile.
__global__ __launch_bounds__(256)
void zact_kernel(const float* __restrict__ x, const float* __restrict__ t,
                 const float* __restrict__ W1, const float* __restrict__ b1,
                 const float* __restrict__ W2, float* __restrict__ act) {
  __shared__ float As[16][68];  // [k][m], +4 pad keeps 16B align, breaks conflicts
  __shared__ float Bs[16][68];  // [k][n]
  const int tx = threadIdx.x, ty = threadIdx.y;
  const int tid = ty * 16 + tx;
  const int m0 = blockIdx.y * 64, n0 = blockIdx.x * 64;
  float acc[4][4] = {};
  const int acol = tid & 15, arow = tid >> 4;   // A loader: 16 cols x 16 rows x4
  const int bn = tid & 63, bk = tid >> 6;       // B loader: 64 cols x 4 k x4
  for (int kb = 0; kb < 528; kb += 16) {
    #pragma unroll
    for (int i = 0; i < 4; i++) {
      int row = arow + i * 16;
      int mr = m0 + row;
      int kc = kb + acol;
      As[acol][row] = (kc < 512) ? x[(size_t)mr * 512 + kc]
                                 : t[(size_t)mr * 16 + (kc - 512)];
    }
    #pragma unroll
    for (int i = 0; i < 4; i++) {
      int kk = bk + i * 4;
      Bs[kk][bn] = W1[(size_t)(kb + kk) * 1024 + n0 + bn];
    }
    __syncthreads();
    #pragma unroll
    for (int kk = 0; kk < 16; kk++) {
      float a[4], bb[4];
      #pragma unroll
      for (int i = 0; i < 4; i++) a[i] = As[kk][ty * 4 + i];
      #pragma unroll
      for (int j = 0; j < 4; j++) bb[j] = Bs[kk][tx * 4 + j];
      #pragma unroll
      for (int i = 0; i < 4; i++)
        #pragma unroll
        for (int j = 0; j < 4; j++)
          acc[i][j] += a[i] * bb[j];
    }
    __syncthreads();
  }
  #pragma unroll
  for (int i = 0; i < 4; i++) {
    int mr = m0 + ty * 4 + i;
    #pragma unroll
    for (int j = 0; j < 4; j++) {
      int n = n0 + tx * 4 + j;
      float z = acc[i][j] + b1[n];
      float th = tanhf(z);
      act[(size_t)mr * 1024 + n] = (1.f - th * th) * W2[n];
    }
  }
}

// C[m,n] = sum_k A[m*K+k] * Bt[n*K+k]   (NT GEMM; used for grad_x and G = P P^T)
__global__ __launch_bounds__(256)
void gemm_nt_kernel(const float* __restrict__ A, const float* __restrict__ Bt,
                    float* __restrict__ C, int M, int N, int K) {
  __shared__ float As[16][68];
  __shared__ float Bs[16][68];
  const int tx = threadIdx.x, ty = threadIdx.y;
  const int tid = ty * 16 + tx;
  const int m0 = blockIdx.y * 64, n0 = blockIdx.x * 64;
  float acc[4][4] = {};
  const int col = tid & 15, rowb = tid >> 4;
  for (int kb = 0; kb < K; kb += 16) {
    #pragma unroll
    for (int i = 0; i < 4; i++) {
      int row = rowb + i * 16;
      As[col][row] = A[(size_t)(m0 + row) * K + kb + col];
      Bs[col][row] = Bt[(size_t)(n0 + row) * K + kb + col];
    }
    __syncthreads();
    #pragma unroll
    for (int kk = 0; kk < 16; kk++) {
      float a[4], bb[4];
      #pragma unroll
      for (int i = 0; i < 4; i++) a[i] = As[kk][ty * 4 + i];
      #pragma unroll
      for (int j = 0; j < 4; j++) bb[j] = Bs[kk][tx * 4 + j];
      #pragma unroll
      for (int i = 0; i < 4; i++)
        #pragma unroll
        for (int j = 0; j < 4; j++)
          acc[i][j] += a[i] * bb[j];
    }
    __syncthreads();
  }
  #pragma unroll
  for (int i = 0; i < 4; i++) {
    #pragma unroll
    for (int j = 0; j < 4; j++) {
      C[(size_t)(m0 + ty * 4 + i) * N + n0 + tx * 4 + j] = acc[i][j];
    }
  }
}

// sq[b] = sum_d P[b,d]^2
__global__ __launch_bounds__(64)
void sq_kernel(const float* __restrict__ P, float* __restrict__ sq) {
  const int b = blockIdx.x, lane = threadIdx.x;
  const float* pr = P + (size_t)b * 512;
  float s = 0.f;
  #pragma unroll
  for (int i = 0; i < 8; i++) { float v = pr[lane + i * 64]; s += v * v; }
  s = bsum64(s);
  if (lane == 0) sq[b] = s;
}

// Per row b: 50 smallest of d2[j] = sq[b]+sq[j]-2*G[b,j]  (the SET; order free)
__global__ __launch_bounds__(256)
void topk_kernel(const float* __restrict__ G, const float* __restrict__ sq,
                 int* __restrict__ idx) {
  const int b = blockIdx.x, tid = threadIdx.x;
  const int lane = tid & 63, wid = tid >> 6;
  float v[8];
  const float sqb = sq[b];
  #pragma unroll
  for (int i = 0; i < 8; i++) {
    int j = tid + i * 256;
    v[i] = sqb + sq[j] - 2.f * G[(size_t)b * 2048 + j];
  }
  __shared__ float swv[4];
  __shared__ int swi[4];
  __shared__ int chosen;
  for (int it = 0; it < K_; it++) {
    float bv = v[0]; int bj = tid;
    #pragma unroll
    for (int i = 1; i < 8; i++) {
      int j = tid + i * 256;
      if (v[i] < bv) { bv = v[i]; bj = j; }
    }
    #pragma unroll
    for (int o = 1; o < 64; o <<= 1) {
      float ov = __shfl_xor(bv, o);
      int oj = __shfl_xor(bj, o);
      if (ov < bv || (ov == bv && oj < bj)) { bv = ov; bj = oj; }
    }
    if (lane == 0) { swv[wid] = bv; swi[wid] = bj; }
    __syncthreads();
    if (tid == 0) {
      float mv = swv[0]; int mj = swi[0];
      for (int wn = 1; wn < 4; wn++) {
        if (swv[wn] < mv || (swv[wn] == mv && swi[wn] < mj)) { mv = swv[wn]; mj = swi[wn]; }
      }
      idx[b * K_ + it] = mj;
      chosen = mj;
    }
    __syncthreads();
    int cj = chosen;
    if ((cj & 255) == tid) v[cj >> 8] = FLT_MAX;
  }
}

// Per batch (one wave): build S = double-centered 50x50 submatrix of G,
// w_k = q_k - mean(q) with q_k = P[a_k].g; one-sided Jacobi on S columns
// (column c in lane c's registers); rotations applied to w give J^T w.
// result_b = sum over top-16 column norms lam of (J^T w)^2 / lam.
__global__ __launch_bounds__(64)
void final_kernel(const float* __restrict__ P, const float* __restrict__ grad,
                  const float* __restrict__ G, const int* __restrict__ idx,
                  float* __restrict__ out) {
  const int b = blockIdx.x;
  const int lane = threadIdx.x;
  __shared__ int ids[K_];
  if (lane < K_) ids[lane] = idx[b * K_ + lane];
  __syncthreads();
  const int ac = (lane < K_) ? ids[lane] : 0;

  // gradient row in registers
  float g[8];
  #pragma unroll
  for (int i = 0; i < 8; i++) g[i] = grad[(size_t)b * 512 + lane + i * 64];

  // q_k = P[a_k] . g  (cooperative dot per k; result parked in lane k)
  float q = 0.f;
  for (int k = 0; k < K_; k++) {
    const float* pr = P + (size_t)ids[k] * 512;
    float s = 0.f;
    #pragma unroll
    for (int i = 0; i < 8; i++) s += pr[lane + i * 64] * g[i];
    s = bsum64(s);
    if (lane == k) q = s;
  }
  float qm = bsum64(lane < K_ ? q : 0.f) * (1.f / K_);
  float w = (lane < K_) ? (q - qm) : 0.f;

  // load column c of the 50x50 G-submatrix
  float f[K_];
  #pragma unroll
  for (int r = 0; r < K_; r++)
    f[r] = (lane < K_) ? G[(size_t)ids[r] * 2048 + ac] : 0.f;

  // double-centering: S = Gs - rowmean - colmean + grandmean (rowmean==colmean by symmetry)
  float cm = 0.f;
  #pragma unroll
  for (int r = 0; r < K_; r++) cm += f[r];
  cm *= (1.f / K_);
  float gs = bsum64(lane < K_ ? cm : 0.f) * (1.f / K_);
  float cs = cm - gs;
  #pragma unroll
  for (int r = 0; r < K_; r++) {
    float rm = __shfl(cm, r);          // all lanes execute the shuffle
    if (lane < K_) f[r] -= rm + cs;
  }

  // one-sided Hestenes Jacobi, round-robin parallel ordering (25 disjoint pairs/round)
  for (int sweep = 0; sweep < NSWEEP; sweep++) {
    for (int r = 0; r < 49; r++) {
      const int kk = (25 * r) % 49;    // the slot that pairs with player 49 this round
      int m;
      if (lane >= K_)      m = lane;   // idle lanes: self
      else if (lane == 49) m = kk;
      else if (lane == kk) m = 49;
      else { m = (r - lane) % 49; if (m < 0) m += 49; }

      float dot = 0.f, nrm = 0.f;
      float y[K_];
      #pragma unroll
      for (int r2 = 0; r2 < K_; r2++) {
        y[r2] = __shfl(f[r2], m);
        dot += f[r2] * y[r2];
        nrm += f[r2] * f[r2];
      }
      float onrm = __shfl(nrm, m);
      const bool isp = lane < m;       // role: lower lane = 'p' (both lanes agree)
      float alpha = isp ? nrm : onrm;
      float beta  = isp ? onrm : nrm;
      float tau = (beta - alpha) / (2.f * dot);
      float sg = (tau >= 0.f) ? 1.f : -1.f;
      float tt = sg / (fabsf(tau) + sqrtf(1.f + tau * tau));
      float cc = 1.f / sqrtf(1.f + tt * tt);
      float ssv = tt * cc;
      float sr = isp ? -ssv : ssv;
      if (lane >= K_ || fabsf(dot) < 1e-20f) { cc = 1.f; sr = 0.f; }
      #pragma unroll
      for (int r2 = 0; r2 < K_; r2++) f[r2] = cc * f[r2] + sr * y[r2];
      float yw = __shfl(w, m);
      w = cc * w + sr * yw;            // accumulates (J^T w)
    }
  }

  // eigenvalues = final column norms (S is PSD); pick top-16; sum w^2/lam
  float n2 = 0.f;
  #pragma unroll
  for (int r2 = 0; r2 < K_; r2++) n2 += f[r2] * f[r2];
  int rank = 0;
  #pragma unroll
  for (int j = 0; j < K_; j++) {
    float vj = __shfl(n2, j);
    rank += (vj > n2 || (vj == n2 && j < lane)) ? 1 : 0;
  }
  float lam = sqrtf(n2);
  float contrib = (lane < K_ && rank < M_) ? (w * w / lam) : 0.f;
  contrib = bsum64(contrib);
  if (lane == 0) atomicAdd(out, contrib * (1.f / B_));
}

extern "C" void kernel_launch(void* const* d_in, const int* in_sizes, int n_in,
                              void* d_out, int out_size, void* d_ws, size_t ws_size,
                              hipStream_t stream) {
  const float* x  = (const float*)d_in[0];
  const float* t  = (const float*)d_in[1];
  const float* P  = (const float*)d_in[2];
  const float* W1 = (const float*)d_in[3];
  const float* b1 = (const float*)d_in[4];
  const float* W2 = (const float*)d_in[5];
  // d_in[6] = b2: does not affect the gradient; unused.
  float* out = (float*)d_out;

  // workspace layout (~29.8 MB)
  float* act  = (float*)d_ws;                 // 2048*1024
  float* grad = act + (size_t)B_ * H_;        // 2048*512
  float* G    = grad + (size_t)B_ * D_;       // 2048*2048
  float* sq   = G + (size_t)B_ * B_;          // 2048
  int*   idx  = (int*)(sq + B_);              // 2048*50

  hipMemsetAsync(d_out, 0, sizeof(float), stream);

  // grad_x
  zact_kernel<<<dim3(H_ / 64, B_ / 64), dim3(16, 16), 0, stream>>>(x, t, W1, b1, W2, act);
  gemm_nt_kernel<<<dim3(D_ / 64, B_ / 64), dim3(16, 16), 0, stream>>>(act, W1, grad, B_, D_, H_);
  // pairwise Gram + kNN
  gemm_nt_kernel<<<dim3(B_ / 64, B_ / 64), dim3(16, 16), 0, stream>>>(P, P, G, B_, B_, D_);
  sq_kernel<<<B_, 64, 0, stream>>>(P, sq);
  topk_kernel<<<B_, 256, 0, stream>>>(G, sq, idx);
  // per-batch spectral projection
  final_kernel<<<B_, 64, 0, stream>>>(P, grad, G, idx, out);
}

// Round 2
// 838.843 us; speedup vs baseline: 1.1486x; 1.1486x over previous
//
#include <hip/hip_runtime.h>
#include <math.h>
#include <float.h>

// Problem constants (match reference)
#define B_ 2048
#define D_ 512
#define T_ 16
#define H_ 1024
#define K_ 50
#define M_ 16
#define NSWEEP 6   // max sweeps; early-exit on convergence (typ. 4-5)

__device__ __forceinline__ float bsum64(float v) {
  #pragma unroll
  for (int o = 1; o < 64; o <<= 1) v += __shfl_xor(v, o);
  return v;
}

// act[b,h] = (1 - tanh^2(z)) * W2[h],  z = concat(x,t)[b,:] @ W1[:,h] + b1[h]
// M=2048, N=1024, K=528.  NN GEMM, 64x64x16 tiles, 4x4 microtile.
__global__ __launch_bounds__(256)
void zact_kernel(const float* __restrict__ x, const float* __restrict__ t,
                 const float* __restrict__ W1, const float* __restrict__ b1,
                 const float* __restrict__ W2, float* __restrict__ act) {
  __shared__ float As[16][68];  // [k][m], +4 pad keeps 16B align, breaks conflicts
  __shared__ float Bs[16][68];  // [k][n]
  const int tx = threadIdx.x, ty = threadIdx.y;
  const int tid = ty * 16 + tx;
  const int m0 = blockIdx.y * 64, n0 = blockIdx.x * 64;
  float acc[4][4] = {};
  const int acol = tid & 15, arow = tid >> 4;   // A loader: 16 cols x 16 rows x4
  const int bn = tid & 63, bk = tid >> 6;       // B loader: 64 cols x 4 k x4
  for (int kb = 0; kb < 528; kb += 16) {
    #pragma unroll
    for (int i = 0; i < 4; i++) {
      int row = arow + i * 16;
      int mr = m0 + row;
      int kc = kb + acol;
      As[acol][row] = (kc < 512) ? x[(size_t)mr * 512 + kc]
                                 : t[(size_t)mr * 16 + (kc - 512)];
    }
    #pragma unroll
    for (int i = 0; i < 4; i++) {
      int kk = bk + i * 4;
      Bs[kk][bn] = W1[(size_t)(kb + kk) * 1024 + n0 + bn];
    }
    __syncthreads();
    #pragma unroll
    for (int kk = 0; kk < 16; kk++) {
      float a[4], bb[4];
      #pragma unroll
      for (int i = 0; i < 4; i++) a[i] = As[kk][ty * 4 + i];
      #pragma unroll
      for (int j = 0; j < 4; j++) bb[j] = Bs[kk][tx * 4 + j];
      #pragma unroll
      for (int i = 0; i < 4; i++)
        #pragma unroll
        for (int j = 0; j < 4; j++)
          acc[i][j] += a[i] * bb[j];
    }
    __syncthreads();
  }
  #pragma unroll
  for (int i = 0; i < 4; i++) {
    int mr = m0 + ty * 4 + i;
    #pragma unroll
    for (int j = 0; j < 4; j++) {
      int n = n0 + tx * 4 + j;
      float z = acc[i][j] + b1[n];
      float th = tanhf(z);
      act[(size_t)mr * 1024 + n] = (1.f - th * th) * W2[n];
    }
  }
}

// C[m,n] = sum_k A[m*K+k] * Bt[n*K+k]   (NT GEMM; used for grad_x and G = P P^T)
__global__ __launch_bounds__(256)
void gemm_nt_kernel(const float* __restrict__ A, const float* __restrict__ Bt,
                    float* __restrict__ C, int M, int N, int K) {
  __shared__ float As[16][68];
  __shared__ float Bs[16][68];
  const int tx = threadIdx.x, ty = threadIdx.y;
  const int tid = ty * 16 + tx;
  const int m0 = blockIdx.y * 64, n0 = blockIdx.x * 64;
  float acc[4][4] = {};
  const int col = tid & 15, rowb = tid >> 4;
  for (int kb = 0; kb < K; kb += 16) {
    #pragma unroll
    for (int i = 0; i < 4; i++) {
      int row = rowb + i * 16;
      As[col][row] = A[(size_t)(m0 + row) * K + kb + col];
      Bs[col][row] = Bt[(size_t)(n0 + row) * K + kb + col];
    }
    __syncthreads();
    #pragma unroll
    for (int kk = 0; kk < 16; kk++) {
      float a[4], bb[4];
      #pragma unroll
      for (int i = 0; i < 4; i++) a[i] = As[kk][ty * 4 + i];
      #pragma unroll
      for (int j = 0; j < 4; j++) bb[j] = Bs[kk][tx * 4 + j];
      #pragma unroll
      for (int i = 0; i < 4; i++)
        #pragma unroll
        for (int j = 0; j < 4; j++)
          acc[i][j] += a[i] * bb[j];
    }
    __syncthreads();
  }
  #pragma unroll
  for (int i = 0; i < 4; i++) {
    #pragma unroll
    for (int j = 0; j < 4; j++) {
      C[(size_t)(m0 + ty * 4 + i) * N + n0 + tx * 4 + j] = acc[i][j];
    }
  }
}

// sq[b] = sum_d P[b,d]^2
__global__ __launch_bounds__(64)
void sq_kernel(const float* __restrict__ P, float* __restrict__ sq) {
  const int b = blockIdx.x, lane = threadIdx.x;
  const float* pr = P + (size_t)b * 512;
  float s = 0.f;
  #pragma unroll
  for (int i = 0; i < 8; i++) { float v = pr[lane + i * 64]; s += v * v; }
  s = bsum64(s);
  if (lane == 0) sq[b] = s;
}

// Per row b: 50 smallest of d2[j] = sq[b]+sq[j]-2*G[b,j]  (the SET; order free)
__global__ __launch_bounds__(256)
void topk_kernel(const float* __restrict__ G, const float* __restrict__ sq,
                 int* __restrict__ idx) {
  const int b = blockIdx.x, tid = threadIdx.x;
  const int lane = tid & 63, wid = tid >> 6;
  float v[8];
  const float sqb = sq[b];
  #pragma unroll
  for (int i = 0; i < 8; i++) {
    int j = tid + i * 256;
    v[i] = sqb + sq[j] - 2.f * G[(size_t)b * 2048 + j];
  }
  __shared__ float swv[4];
  __shared__ int swi[4];
  __shared__ int chosen;
  for (int it = 0; it < K_; it++) {
    float bv = v[0]; int bj = tid;
    #pragma unroll
    for (int i = 1; i < 8; i++) {
      int j = tid + i * 256;
      if (v[i] < bv) { bv = v[i]; bj = j; }
    }
    #pragma unroll
    for (int o = 1; o < 64; o <<= 1) {
      float ov = __shfl_xor(bv, o);
      int oj = __shfl_xor(bj, o);
      if (ov < bv || (ov == bv && oj < bj)) { bv = ov; bj = oj; }
    }
    if (lane == 0) { swv[wid] = bv; swi[wid] = bj; }
    __syncthreads();
    if (tid == 0) {
      float mv = swv[0]; int mj = swi[0];
      for (int wn = 1; wn < 4; wn++) {
        if (swv[wn] < mv || (swv[wn] == mv && swi[wn] < mj)) { mv = swv[wn]; mj = swi[wn]; }
      }
      idx[b * K_ + it] = mj;
      chosen = mj;
    }
    __syncthreads();
    int cj = chosen;
    if ((cj & 255) == tid) v[cj >> 8] = FLT_MAX;
  }
}

// Per batch (one wave): build S = double-centered 50x50 submatrix of G,
// w_k = q_k - mean(q) with q_k = P[a_k].g; one-sided Jacobi on S columns
// (column c in lane c's registers); rotations applied to w give J^T w.
// result_b = sum over top-16 column norms lam of (J^T w)^2 / lam.
__global__ __launch_bounds__(64)
void final_kernel(const float* __restrict__ P, const float* __restrict__ grad,
                  const float* __restrict__ G, const int* __restrict__ idx,
                  float* __restrict__ out) {
  const int b = blockIdx.x;
  const int lane = threadIdx.x;
  __shared__ int ids[K_];
  if (lane < K_) ids[lane] = idx[b * K_ + lane];
  __syncthreads();
  const int ac = (lane < K_) ? ids[lane] : 0;

  // gradient row in registers
  float g[8];
  #pragma unroll
  for (int i = 0; i < 8; i++) g[i] = grad[(size_t)b * 512 + lane + i * 64];

  // q_k = P[a_k] . g  (cooperative dot per k; result parked in lane k)
  float q = 0.f;
  for (int k = 0; k < K_; k++) {
    const float* pr = P + (size_t)ids[k] * 512;
    float s = 0.f;
    #pragma unroll
    for (int i = 0; i < 8; i++) s += pr[lane + i * 64] * g[i];
    s = bsum64(s);
    if (lane == k) q = s;
  }
  float qm = bsum64(lane < K_ ? q : 0.f) * (1.f / K_);
  float w = (lane < K_) ? (q - qm) : 0.f;

  // load column c of the 50x50 G-submatrix
  float f[K_];
  #pragma unroll
  for (int r = 0; r < K_; r++)
    f[r] = (lane < K_) ? G[(size_t)ids[r] * 2048 + ac] : 0.f;

  // double-centering: S = Gs - rowmean - colmean + grandmean (rowmean==colmean by symmetry)
  float cm = 0.f;
  #pragma unroll
  for (int r = 0; r < K_; r++) cm += f[r];
  cm *= (1.f / K_);
  float gs = bsum64(lane < K_ ? cm : 0.f) * (1.f / K_);
  float cs = cm - gs;
  #pragma unroll
  for (int r = 0; r < K_; r++) {
    float rm = __shfl(cm, r);          // all lanes execute the shuffle
    if (lane < K_) f[r] -= rm + cs;
  }

  // initial column squared norm (tracked incrementally through rotations;
  // exact norms are recomputed from f after the loop for the eigenvalues)
  float nrm = 0.f;
  #pragma unroll
  for (int r = 0; r < K_; r++) nrm += f[r] * f[r];

  // one-sided Hestenes Jacobi, round-robin parallel ordering (25 disjoint
  // pairs/round). Early-exit when all pair ratios dot^2/(a*b) <= 1e-9.
  for (int sweep = 0; sweep < NSWEEP; sweep++) {
    bool anybad = false;
    for (int r = 0; r < 49; r++) {
      const int kk = (25 * r) % 49;    // the slot that pairs with player 49 this round
      int m;
      if (lane >= K_)      m = lane;   // idle lanes: self
      else if (lane == 49) m = kk;
      else if (lane == kk) m = 49;
      else { m = (r - lane) % 49; if (m < 0) m += 49; }

      float dot = 0.f;
      float y[K_];
      #pragma unroll
      for (int r2 = 0; r2 < K_; r2++) {
        y[r2] = __shfl(f[r2], m);
        dot += f[r2] * y[r2];
      }
      float onrm = __shfl(nrm, m);
      anybad = anybad || (dot * dot > 1e-9f * nrm * onrm);

      const bool isp = lane < m;       // role: lower lane = 'p' (both lanes agree)
      float alpha = isp ? nrm : onrm;
      float beta  = isp ? onrm : nrm;
      float tau = (beta - alpha) / (2.f * dot);
      float sg = (tau >= 0.f) ? 1.f : -1.f;
      float tt = sg / (fabsf(tau) + sqrtf(1.f + tau * tau));
      float cc = 1.f / sqrtf(1.f + tt * tt);
      float ssv = tt * cc;
      float sr = isp ? -ssv : ssv;
      if (lane >= K_ || fabsf(dot) < 1e-20f) { cc = 1.f; sr = 0.f; }
      #pragma unroll
      for (int r2 = 0; r2 < K_; r2++) f[r2] = cc * f[r2] + sr * y[r2];
      float yw = __shfl(w, m);
      w = cc * w + sr * yw;            // accumulates (J^T w)
      // incremental norm update (same closed form for both roles)
      nrm = cc * cc * nrm + sr * sr * onrm + 2.f * cc * sr * dot;
    }
    if (__ballot(anybad) == 0ull) break;   // wave-uniform convergence test
  }

  // eigenvalues = final column norms (S is PSD); pick top-16; sum w^2/lam
  float n2 = 0.f;
  #pragma unroll
  for (int r2 = 0; r2 < K_; r2++) n2 += f[r2] * f[r2];
  int rank = 0;
  #pragma unroll
  for (int j = 0; j < K_; j++) {
    float vj = __shfl(n2, j);
    rank += (vj > n2 || (vj == n2 && j < lane)) ? 1 : 0;
  }
  float lam = sqrtf(n2);
  float contrib = (lane < K_ && rank < M_) ? (w * w / lam) : 0.f;
  contrib = bsum64(contrib);
  if (lane == 0) atomicAdd(out, contrib * (1.f / B_));
}

extern "C" void kernel_launch(void* const* d_in, const int* in_sizes, int n_in,
                              void* d_out, int out_size, void* d_ws, size_t ws_size,
                              hipStream_t stream) {
  const float* x  = (const float*)d_in[0];
  const float* t  = (const float*)d_in[1];
  const float* P  = (const float*)d_in[2];
  const float* W1 = (const float*)d_in[3];
  const float* b1 = (const float*)d_in[4];
  const float* W2 = (const float*)d_in[5];
  // d_in[6] = b2: does not affect the gradient; unused.
  float* out = (float*)d_out;

  // workspace layout (~29.8 MB)
  float* act  = (float*)d_ws;                 // 2048*1024
  float* grad = act + (size_t)B_ * H_;        // 2048*512
  float* G    = grad + (size_t)B_ * D_;       // 2048*2048
  float* sq   = G + (size_t)B_ * B_;          // 2048
  int*   idx  = (int*)(sq + B_);              // 2048*50

  hipMemsetAsync(d_out, 0, sizeof(float), stream);

  // grad_x
  zact_kernel<<<dim3(H_ / 64, B_ / 64), dim3(16, 16), 0, stream>>>(x, t, W1, b1, W2, act);
  gemm_nt_kernel<<<dim3(D_ / 64, B_ / 64), dim3(16, 16), 0, stream>>>(act, W1, grad, B_, D_, H_);
  // pairwise Gram + kNN
  gemm_nt_kernel<<<dim3(B_ / 64, B_ / 64), dim3(16, 16), 0, stream>>>(P, P, G, B_, B_, D_);
  sq_kernel<<<B_, 64, 0, stream>>>(P, sq);
  topk_kernel<<<B_, 256, 0, stream>>>(G, sq, idx);
  // per-batch spectral projection
  final_kernel<<<B_, 64, 0, stream>>>(P, grad, G, idx, out);
}

// Round 3
// 568.116 us; speedup vs baseline: 1.6959x; 1.4765x over previous
//
#include <hip/hip_runtime.h>
#include <math.h>
#include <float.h>

// Problem constants (match reference)
#define B_ 2048
#define D_ 512
#define T_ 16
#define H_ 1024
#define K_ 50
#define M_ 16
#define NSWEEP 3   // fixed; 3 round-robin sweeps -> off-diag ~1e-3, R err ~1e-4 rel

__device__ __forceinline__ float bsum64(float v) {
  #pragma unroll
  for (int o = 1; o < 64; o <<= 1) v += __shfl_xor(v, o);
  return v;
}

// act[b,h] = (1 - tanh^2(z)) * W2[h],  z = concat(x,t)[b,:] @ W1[:,h] + b1[h]
// M=2048, N=1024, K=528.  NN GEMM, 64x64x16 tiles, 4x4 microtile.
__global__ __launch_bounds__(256)
void zact_kernel(const float* __restrict__ x, const float* __restrict__ t,
                 const float* __restrict__ W1, const float* __restrict__ b1,
                 const float* __restrict__ W2, float* __restrict__ act) {
  __shared__ float As[16][68];  // [k][m], +4 pad keeps 16B align, breaks conflicts
  __shared__ float Bs[16][68];  // [k][n]
  const int tx = threadIdx.x, ty = threadIdx.y;
  const int tid = ty * 16 + tx;
  const int m0 = blockIdx.y * 64, n0 = blockIdx.x * 64;
  float acc[4][4] = {};
  const int acol = tid & 15, arow = tid >> 4;   // A loader: 16 cols x 16 rows x4
  const int bn = tid & 63, bk = tid >> 6;       // B loader: 64 cols x 4 k x4
  for (int kb = 0; kb < 528; kb += 16) {
    #pragma unroll
    for (int i = 0; i < 4; i++) {
      int row = arow + i * 16;
      int mr = m0 + row;
      int kc = kb + acol;
      As[acol][row] = (kc < 512) ? x[(size_t)mr * 512 + kc]
                                 : t[(size_t)mr * 16 + (kc - 512)];
    }
    #pragma unroll
    for (int i = 0; i < 4; i++) {
      int kk = bk + i * 4;
      Bs[kk][bn] = W1[(size_t)(kb + kk) * 1024 + n0 + bn];
    }
    __syncthreads();
    #pragma unroll
    for (int kk = 0; kk < 16; kk++) {
      float a[4], bb[4];
      #pragma unroll
      for (int i = 0; i < 4; i++) a[i] = As[kk][ty * 4 + i];
      #pragma unroll
      for (int j = 0; j < 4; j++) bb[j] = Bs[kk][tx * 4 + j];
      #pragma unroll
      for (int i = 0; i < 4; i++)
        #pragma unroll
        for (int j = 0; j < 4; j++)
          acc[i][j] += a[i] * bb[j];
    }
    __syncthreads();
  }
  #pragma unroll
  for (int i = 0; i < 4; i++) {
    int mr = m0 + ty * 4 + i;
    #pragma unroll
    for (int j = 0; j < 4; j++) {
      int n = n0 + tx * 4 + j;
      float z = acc[i][j] + b1[n];
      float th = tanhf(z);
      act[(size_t)mr * 1024 + n] = (1.f - th * th) * W2[n];
    }
  }
}

// C[m,n] = sum_k A[m*K+k] * Bt[n*K+k]   (NT GEMM; used for grad_x and G = P P^T)
__global__ __launch_bounds__(256)
void gemm_nt_kernel(const float* __restrict__ A, const float* __restrict__ Bt,
                    float* __restrict__ C, int M, int N, int K) {
  __shared__ float As[16][68];
  __shared__ float Bs[16][68];
  const int tx = threadIdx.x, ty = threadIdx.y;
  const int tid = ty * 16 + tx;
  const int m0 = blockIdx.y * 64, n0 = blockIdx.x * 64;
  float acc[4][4] = {};
  const int col = tid & 15, rowb = tid >> 4;
  for (int kb = 0; kb < K; kb += 16) {
    #pragma unroll
    for (int i = 0; i < 4; i++) {
      int row = rowb + i * 16;
      As[col][row] = A[(size_t)(m0 + row) * K + kb + col];
      Bs[col][row] = Bt[(size_t)(n0 + row) * K + kb + col];
    }
    __syncthreads();
    #pragma unroll
    for (int kk = 0; kk < 16; kk++) {
      float a[4], bb[4];
      #pragma unroll
      for (int i = 0; i < 4; i++) a[i] = As[kk][ty * 4 + i];
      #pragma unroll
      for (int j = 0; j < 4; j++) bb[j] = Bs[kk][tx * 4 + j];
      #pragma unroll
      for (int i = 0; i < 4; i++)
        #pragma unroll
        for (int j = 0; j < 4; j++)
          acc[i][j] += a[i] * bb[j];
    }
    __syncthreads();
  }
  #pragma unroll
  for (int i = 0; i < 4; i++) {
    #pragma unroll
    for (int j = 0; j < 4; j++) {
      C[(size_t)(m0 + ty * 4 + i) * N + n0 + tx * 4 + j] = acc[i][j];
    }
  }
}

// sq[b] = sum_d P[b,d]^2
__global__ __launch_bounds__(64)
void sq_kernel(const float* __restrict__ P, float* __restrict__ sq) {
  const int b = blockIdx.x, lane = threadIdx.x;
  const float* pr = P + (size_t)b * 512;
  float s = 0.f;
  #pragma unroll
  for (int i = 0; i < 8; i++) { float v = pr[lane + i * 64]; s += v * v; }
  s = bsum64(s);
  if (lane == 0) sq[b] = s;
}

// Per row b: 50 smallest of d2[j] = sq[b]+sq[j]-2*G[b,j]  (the SET; order free)
__global__ __launch_bounds__(256)
void topk_kernel(const float* __restrict__ G, const float* __restrict__ sq,
                 int* __restrict__ idx) {
  const int b = blockIdx.x, tid = threadIdx.x;
  const int lane = tid & 63, wid = tid >> 6;
  float v[8];
  const float sqb = sq[b];
  #pragma unroll
  for (int i = 0; i < 8; i++) {
    int j = tid + i * 256;
    v[i] = sqb + sq[j] - 2.f * G[(size_t)b * 2048 + j];
  }
  __shared__ float swv[4];
  __shared__ int swi[4];
  __shared__ int chosen;
  for (int it = 0; it < K_; it++) {
    float bv = v[0]; int bj = tid;
    #pragma unroll
    for (int i = 1; i < 8; i++) {
      int j = tid + i * 256;
      if (v[i] < bv) { bv = v[i]; bj = j; }
    }
    #pragma unroll
    for (int o = 1; o < 64; o <<= 1) {
      float ov = __shfl_xor(bv, o);
      int oj = __shfl_xor(bj, o);
      if (ov < bv || (ov == bv && oj < bj)) { bv = ov; bj = oj; }
    }
    if (lane == 0) { swv[wid] = bv; swi[wid] = bj; }
    __syncthreads();
    if (tid == 0) {
      float mv = swv[0]; int mj = swi[0];
      for (int wn = 1; wn < 4; wn++) {
        if (swv[wn] < mv || (swv[wn] == mv && swi[wn] < mj)) { mv = swv[wn]; mj = swi[wn]; }
      }
      idx[b * K_ + it] = mj;
      chosen = mj;
    }
    __syncthreads();
    int cj = chosen;
    if ((cj & 255) == tid) v[cj >> 8] = FLT_MAX;
  }
}

// Per batch (one wave): build S = double-centered 50x50 submatrix of G,
// w_k = q_k - mean(q) with q_k = P[a_k].g; one-sided Jacobi on S columns
// (column c in lane c's registers); rotations applied to w give J^T w.
// result_b = sum over top-16 column norms lam of (J^T w)^2 / lam.
// launch_bounds(64,2): min 2 waves/EU -> VGPR cap 256 so f[50]+y[50] stay
// in registers (at the default cap of 88 the y[] array spilled to scratch,
// ~15 GB of vmem traffic across the dispatch — dominated round-2 runtime).
__global__ __launch_bounds__(64, 2)
void final_kernel(const float* __restrict__ P, const float* __restrict__ grad,
                  const float* __restrict__ G, const int* __restrict__ idx,
                  float* __restrict__ out) {
  const int b = blockIdx.x;
  const int lane = threadIdx.x;
  __shared__ int ids[K_];
  if (lane < K_) ids[lane] = idx[b * K_ + lane];
  __syncthreads();
  const int ac = (lane < K_) ? ids[lane] : 0;

  // gradient row in registers
  float g[8];
  #pragma unroll
  for (int i = 0; i < 8; i++) g[i] = grad[(size_t)b * 512 + lane + i * 64];

  // q_k = P[a_k] . g  (cooperative dot per k; result parked in lane k)
  float q = 0.f;
  for (int k = 0; k < K_; k++) {
    const float* pr = P + (size_t)ids[k] * 512;
    float s = 0.f;
    #pragma unroll
    for (int i = 0; i < 8; i++) s += pr[lane + i * 64] * g[i];
    s = bsum64(s);
    if (lane == k) q = s;
  }
  float qm = bsum64(lane < K_ ? q : 0.f) * (1.f / K_);
  float w = (lane < K_) ? (q - qm) : 0.f;

  // load column c of the 50x50 G-submatrix
  float f[K_];
  #pragma unroll
  for (int r = 0; r < K_; r++)
    f[r] = (lane < K_) ? G[(size_t)ids[r] * 2048 + ac] : 0.f;

  // double-centering: S = Gs - rowmean - colmean + grandmean (rowmean==colmean by symmetry)
  float cm = 0.f;
  #pragma unroll
  for (int r = 0; r < K_; r++) cm += f[r];
  cm *= (1.f / K_);
  float gs = bsum64(lane < K_ ? cm : 0.f) * (1.f / K_);
  float cs = cm - gs;
  #pragma unroll
  for (int r = 0; r < K_; r++) {
    float rm = __shfl(cm, r);          // all lanes execute the shuffle
    if (lane < K_) f[r] -= rm + cs;
  }

  // initial column squared norm (tracked incrementally through rotations;
  // exact norms are recomputed from f after the loop for the eigenvalues)
  float nrm = 0.f;
  #pragma unroll
  for (int r = 0; r < K_; r++) nrm += f[r] * f[r];

  // one-sided Hestenes Jacobi, round-robin parallel ordering (25 disjoint
  // pairs/round), NSWEEP fixed sweeps.
  for (int sweep = 0; sweep < NSWEEP; sweep++) {
    for (int r = 0; r < 49; r++) {
      const int kk = (25 * r) % 49;    // the slot that pairs with player 49 this round
      int m;
      if (lane >= K_)      m = lane;   // idle lanes: self
      else if (lane == 49) m = kk;
      else if (lane == kk) m = 49;
      else { m = (r - lane) % 49; if (m < 0) m += 49; }

      // partner column via single bpermute per element; y[] stays in VGPRs
      float y[K_];
      float d0 = 0.f, d1 = 0.f, d2 = 0.f, d3 = 0.f;   // 4-way ILP on the dot
      #pragma unroll
      for (int r2 = 0; r2 < K_; r2 += 2) {
        y[r2]     = __shfl(f[r2], m);
        y[r2 + 1] = __shfl(f[r2 + 1], m);
        d0 += f[r2] * y[r2];
        d1 += f[r2 + 1] * y[r2 + 1];
      }
      float dot = (d0 + d1) + (d2 + d3);
      float onrm = __shfl(nrm, m);

      const bool isp = lane < m;       // role: lower lane = 'p' (both lanes agree)
      float alpha = isp ? nrm : onrm;
      float beta  = isp ? onrm : nrm;
      float tau = (beta - alpha) / (2.f * dot);
      float sg = (tau >= 0.f) ? 1.f : -1.f;
      float tt = sg / (fabsf(tau) + sqrtf(1.f + tau * tau));
      float cc = 1.f / sqrtf(1.f + tt * tt);
      float ssv = tt * cc;
      float sr = isp ? -ssv : ssv;
      if (lane >= K_ || fabsf(dot) < 1e-20f) { cc = 1.f; sr = 0.f; }
      #pragma unroll
      for (int r2 = 0; r2 < K_; r2++) f[r2] = cc * f[r2] + sr * y[r2];
      float yw = __shfl(w, m);
      w = cc * w + sr * yw;            // accumulates (J^T w)
      // incremental norm update (same closed form for both roles)
      nrm = cc * cc * nrm + sr * sr * onrm + 2.f * cc * sr * dot;
    }
  }

  // eigenvalues = final column norms (S is PSD); pick top-16; sum w^2/lam
  float n2 = 0.f;
  #pragma unroll
  for (int r2 = 0; r2 < K_; r2++) n2 += f[r2] * f[r2];
  int rank = 0;
  #pragma unroll
  for (int j = 0; j < K_; j++) {
    float vj = __shfl(n2, j);
    rank += (vj > n2 || (vj == n2 && j < lane)) ? 1 : 0;
  }
  float lam = sqrtf(n2);
  float contrib = (lane < K_ && rank < M_) ? (w * w / lam) : 0.f;
  contrib = bsum64(contrib);
  if (lane == 0) atomicAdd(out, contrib * (1.f / B_));
}

extern "C" void kernel_launch(void* const* d_in, const int* in_sizes, int n_in,
                              void* d_out, int out_size, void* d_ws, size_t ws_size,
                              hipStream_t stream) {
  const float* x  = (const float*)d_in[0];
  const float* t  = (const float*)d_in[1];
  const float* P  = (const float*)d_in[2];
  const float* W1 = (const float*)d_in[3];
  const float* b1 = (const float*)d_in[4];
  const float* W2 = (const float*)d_in[5];
  // d_in[6] = b2: does not affect the gradient; unused.
  float* out = (float*)d_out;

  // workspace layout (~29.8 MB)
  float* act  = (float*)d_ws;                 // 2048*1024
  float* grad = act + (size_t)B_ * H_;        // 2048*512
  float* G    = grad + (size_t)B_ * D_;       // 2048*2048
  float* sq   = G + (size_t)B_ * B_;          // 2048
  int*   idx  = (int*)(sq + B_);              // 2048*50

  hipMemsetAsync(d_out, 0, sizeof(float), stream);

  // grad_x
  zact_kernel<<<dim3(H_ / 64, B_ / 64), dim3(16, 16), 0, stream>>>(x, t, W1, b1, W2, act);
  gemm_nt_kernel<<<dim3(D_ / 64, B_ / 64), dim3(16, 16), 0, stream>>>(act, W1, grad, B_, D_, H_);
  // pairwise Gram + kNN
  gemm_nt_kernel<<<dim3(B_ / 64, B_ / 64), dim3(16, 16), 0, stream>>>(P, P, G, B_, B_, D_);
  sq_kernel<<<B_, 64, 0, stream>>>(P, sq);
  topk_kernel<<<B_, 256, 0, stream>>>(G, sq, idx);
  // per-batch spectral projection
  final_kernel<<<B_, 64, 0, stream>>>(P, grad, G, idx, out);
}